// Round 10
// baseline (89.789 us; speedup 1.0000x reference)
//
#include <hip/hip_runtime.h>

typedef float f32x4 __attribute__((ext_vector_type(4)));
typedef int   i32x4 __attribute__((ext_vector_type(4)));
typedef int   i32x8 __attribute__((ext_vector_type(8)));

#define D 128
#define GBLK 2048   // 32 row-panels x 64 col-tiles

// ---------------------------------------------------------------------------
// Normalize: one block = 16 rows x 16 lanes. fp8(e4m3) normalized rows -> ws,
// exact-f32 diag partial -> diagP[bid]; block 0 zeroes the gemm ticket.
// (Validated verbatim since R5: absmax 0.0.)
// ---------------------------------------------------------------------------
__global__ void normalize_diag_kernel(const float* __restrict__ anc,
                                      const float* __restrict__ pos,
                                      unsigned char* __restrict__ wsA,
                                      unsigned char* __restrict__ wsP,
                                      float* __restrict__ diagP,
                                      int* __restrict__ counter) {
  if (blockIdx.x == 0 && threadIdx.x == 0)
    __hip_atomic_store(counter, 0, __ATOMIC_RELAXED, __HIP_MEMORY_SCOPE_AGENT);
  __shared__ float rowc[16];
  const int t = threadIdx.x;
  const int rl = t >> 4, l16 = t & 15;
  const int row = blockIdx.x * 16 + rl;
  const float* ar = anc + (size_t)row * D + l16 * 8;
  const float* pr = pos + (size_t)row * D + l16 * 8;
  float4 a0 = *(const float4*)ar, a1 = *(const float4*)(ar + 4);
  float4 p0 = *(const float4*)pr, p1 = *(const float4*)(pr + 4);
  float av[8] = {a0.x, a0.y, a0.z, a0.w, a1.x, a1.y, a1.z, a1.w};
  float pv[8] = {p0.x, p0.y, p0.z, p0.w, p1.x, p1.y, p1.z, p1.w};
  float ssa = 0.f, ssp = 0.f;
#pragma unroll
  for (int k = 0; k < 8; ++k) { ssa += av[k] * av[k]; ssp += pv[k] * pv[k]; }
#pragma unroll
  for (int off = 1; off < 16; off <<= 1) {
    ssa += __shfl_xor(ssa, off);
    ssp += __shfl_xor(ssp, off);
  }
  const float sa = 1.f / fmaxf(sqrtf(ssa), 1e-8f);
  const float sp = 1.f / fmaxf(sqrtf(ssp), 1e-8f);
  float an[8], pn[8];
  float dot = 0.f;
#pragma unroll
  for (int k = 0; k < 8; ++k) {
    an[k] = av[k] * sa;
    pn[k] = pv[k] * sp;
    dot += an[k] * pn[k];
  }
  int wa0 = __builtin_amdgcn_cvt_pk_fp8_f32(an[0], an[1], 0, false);
  wa0 = __builtin_amdgcn_cvt_pk_fp8_f32(an[2], an[3], wa0, true);
  int wa1 = __builtin_amdgcn_cvt_pk_fp8_f32(an[4], an[5], 0, false);
  wa1 = __builtin_amdgcn_cvt_pk_fp8_f32(an[6], an[7], wa1, true);
  int wp0 = __builtin_amdgcn_cvt_pk_fp8_f32(pn[0], pn[1], 0, false);
  wp0 = __builtin_amdgcn_cvt_pk_fp8_f32(pn[2], pn[3], wp0, true);
  int wp1 = __builtin_amdgcn_cvt_pk_fp8_f32(pn[4], pn[5], 0, false);
  wp1 = __builtin_amdgcn_cvt_pk_fp8_f32(pn[6], pn[7], wp1, true);
  *(int2*)(wsA + (size_t)row * D + l16 * 8) = make_int2(wa0, wa1);
  *(int2*)(wsP + (size_t)row * D + l16 * 8) = make_int2(wp0, wp1);
#pragma unroll
  for (int off = 1; off < 16; off <<= 1) dot += __shfl_xor(dot, off);
  if (l16 == 0) rowc[rl] = 1.f - dot - fmaxf(dot, 0.f);
  __syncthreads();
  if (t == 0) {
    float s = 0.f;
#pragma unroll
    for (int i = 0; i < 16; ++i) s += rowc[i];
    diagP[blockIdx.x] = s;
  }
}

// ---------------------------------------------------------------------------
// fp8 MX GEMM, occupancy-first: 2048 independent blocks (256 thr = 4 waves,
// 2x2), block tile 256x128, wave tile 128x64. LDS 48KB -> 3 blocks/CU =
// 12 waves/CU; inter-block TLP hides staging latency (no K-loop: K=128 is
// ONE mfma_scale per fragment pair). bid%8 == ct%8 pins all blocks sharing
// a B-slice to one XCD's L2. Epilogue: relu-sum partial + ticket finalize.
// ---------------------------------------------------------------------------
__global__ __launch_bounds__(256, 3) void gemm_relu_sum_kernel(
    const unsigned char* __restrict__ wsA,
    const unsigned char* __restrict__ wsP,
    float* __restrict__ partials, const float* __restrict__ diagP,
    int* __restrict__ counter, float* __restrict__ out, float invBB) {
  __shared__ __align__(16) unsigned char ldsA[256 * 128];   // 32 KB
  __shared__ __align__(16) unsigned char ldsB[128 * 128];   // 16 KB
  __shared__ float wpart[4];
  __shared__ int lastFlag;
  const int tid = threadIdx.x;
  const int bid = blockIdx.x;
  const int w = tid >> 6, l = tid & 63;
  const int r16 = l & 15, kg = l >> 4;
  const int wrow = w >> 1, wcol = w & 1;   // wave tile 128 rows x 64 cols
  const int rp = bid >> 6;                 // row panel 0..31 (256 rows)
  const int ct = bid & 63;                 // col tile 0..63 (128 cols)

  // ---- stage A (256x128 fp8 = 32KB, 8 insts) + B (128x128 = 16KB, 4 insts)
  const unsigned char* gA = wsA + (size_t)rp * 256 * D;
  const unsigned char* gB = wsP + (size_t)ct * 128 * D;
#pragma unroll
  for (int it = 0; it < 8; ++it) {
    const int g = it * 256 + tid;          // 16B chunk 0..2047
    const int r = g >> 3, sl = g & 7;
    const int goff = r * 128 + ((sl ^ (r & 7)) * 16);
    const int lbase = (it * 256 + w * 64) * 16;
    __builtin_amdgcn_global_load_lds(
        (const __attribute__((address_space(1))) char*)(gA + goff),
        (__attribute__((address_space(3))) char*)((char*)ldsA + lbase), 16, 0, 0);
  }
#pragma unroll
  for (int it = 0; it < 4; ++it) {
    const int g = it * 256 + tid;          // 16B chunk 0..1023
    const int r = g >> 3, sl = g & 7;
    const int goff = r * 128 + ((sl ^ (r & 7)) * 16);
    const int lbase = (it * 256 + w * 64) * 16;
    __builtin_amdgcn_global_load_lds(
        (const __attribute__((address_space(1))) char*)(gB + goff),
        (__attribute__((address_space(3))) char*)((char*)ldsB + lbase), 16, 0, 0);
  }
  __syncthreads();

  // ---- fragments (validated formulas: slot (2kg[+1]) ^ (r&7))
  i32x8 af[8];
#pragma unroll
  for (int m = 0; m < 8; ++m) {
    const int r = wrow * 128 + m * 16 + r16;
    const unsigned char* base = (const unsigned char*)ldsA + r * 128;
    i32x4 lo = *(const i32x4*)(base + (((2 * kg) ^ (r & 7)) * 16));
    i32x4 hi = *(const i32x4*)(base + (((2 * kg + 1) ^ (r & 7)) * 16));
    af[m] = __builtin_shufflevector(lo, hi, 0, 1, 2, 3, 4, 5, 6, 7);
  }
  i32x8 bfr[4];
#pragma unroll
  for (int n = 0; n < 4; ++n) {
    const int r = wcol * 64 + n * 16 + r16;
    const unsigned char* base = (const unsigned char*)ldsB + r * 128;
    i32x4 lo = *(const i32x4*)(base + (((2 * kg) ^ (r & 7)) * 16));
    i32x4 hi = *(const i32x4*)(base + (((2 * kg + 1) ^ (r & 7)) * 16));
    bfr[n] = __builtin_shufflevector(lo, hi, 0, 1, 2, 3, 4, 5, 6, 7);
  }

  // ---- 32 independent MFMAs (full K=128 each), then relu-sum
  f32x4 acc[8][4] = {};
  __builtin_amdgcn_s_setprio(1);
#pragma unroll
  for (int m = 0; m < 8; ++m)
#pragma unroll
    for (int n = 0; n < 4; ++n)
      acc[m][n] = __builtin_amdgcn_mfma_scale_f32_16x16x128_f8f6f4(
          af[m], bfr[n], acc[m][n], 0, 0,   // cbsz=fp8, blgp=fp8
          0, 0x7f7f7f7f, 0, 0x7f7f7f7f);    // scales = 1.0
  __builtin_amdgcn_s_setprio(0);

  float s0 = 0.f, s1 = 0.f, s2 = 0.f, s3 = 0.f;
#pragma unroll
  for (int m = 0; m < 8; ++m)
#pragma unroll
    for (int n = 0; n < 4; ++n) {
      s0 += fmaxf(acc[m][n][0], 0.f);
      s1 += fmaxf(acc[m][n][1], 0.f);
      s2 += fmaxf(acc[m][n][2], 0.f);
      s3 += fmaxf(acc[m][n][3], 0.f);
    }

  // ---- block partial + ticket-fused finalize (R8-validated pattern)
  float s = (s0 + s1) + (s2 + s3);
#pragma unroll
  for (int off = 32; off >= 1; off >>= 1) s += __shfl_xor(s, off);
  if (l == 0) wpart[w] = s;
  __syncthreads();
  if (tid == 0) {
    const float b = wpart[0] + wpart[1] + wpart[2] + wpart[3];
    __hip_atomic_store(&partials[bid], b, __ATOMIC_RELAXED,
                       __HIP_MEMORY_SCOPE_AGENT);
    __threadfence();
    const int ticket = __hip_atomic_fetch_add(counter, 1, __ATOMIC_ACQ_REL,
                                              __HIP_MEMORY_SCOPE_AGENT);
    lastFlag = (ticket == GBLK - 1) ? 1 : 0;
  }
  __syncthreads();

  if (lastFlag) {
    __threadfence();
    float v = 0.f;
    for (int i = tid; i < GBLK; i += 256)
      v += __hip_atomic_load(&partials[i], __ATOMIC_RELAXED,
                             __HIP_MEMORY_SCOPE_AGENT);
    for (int i = tid; i < 512; i += 256) v += diagP[i];
#pragma unroll
    for (int off = 32; off >= 1; off >>= 1) v += __shfl_xor(v, off);
    if (l == 0) wpart[w] = v;
    __syncthreads();
    if (tid == 0)
      out[0] = (wpart[0] + wpart[1] + wpart[2] + wpart[3]) * invBB;
  }
}

extern "C" void kernel_launch(void* const* d_in, const int* in_sizes, int n_in,
                              void* d_out, int out_size, void* d_ws, size_t ws_size,
                              hipStream_t stream) {
  const float* pos = (const float*)d_in[0];  // hid_positive
  const float* anc = (const float*)d_in[1];  // hid_anchor
  const int B = in_sizes[0] / D;             // 8192

  char* ws = (char*)d_ws;
  unsigned char* wsA = (unsigned char*)ws;                      // B*D fp8 (1MB)
  unsigned char* wsP = (unsigned char*)(ws + (size_t)B * D);    // B*D fp8 (1MB)
  float* partials = (float*)(ws + (size_t)2 * B * D);           // 2048 f32
  float* diagP = partials + GBLK;                               // 512 f32
  int* counter = (int*)(diagP + 512);

  const int nDiag = B / 16;                  // 512
  const float invBB = 1.0f / ((float)B * (float)B);

  normalize_diag_kernel<<<nDiag, 256, 0, stream>>>(anc, pos, wsA, wsP, diagP,
                                                   counter);
  gemm_relu_sum_kernel<<<GBLK, 256, 0, stream>>>(wsA, wsP, partials, diagP,
                                                 counter, (float*)d_out, invBB);
}

// Round 11
// 36.119 us; speedup vs baseline: 2.4860x; 2.4860x over previous
//
#include <hip/hip_runtime.h>

typedef float f32x4 __attribute__((ext_vector_type(4)));
typedef int   i32x4 __attribute__((ext_vector_type(4)));
typedef int   i32x8 __attribute__((ext_vector_type(8)));

#define D 128
#define GBLK 512   // 64 row-panels x 8 col-groups

// ---------------------------------------------------------------------------
// Normalize: one block = 16 rows x 16 lanes. fp8(e4m3) normalized rows -> ws,
// exact-f32 diag partial -> diagP[bid]; block 0 zeroes the gemm ticket.
// (Validated verbatim since R5: absmax 0.0.)
// ---------------------------------------------------------------------------
__global__ void normalize_diag_kernel(const float* __restrict__ anc,
                                      const float* __restrict__ pos,
                                      unsigned char* __restrict__ wsA,
                                      unsigned char* __restrict__ wsP,
                                      float* __restrict__ diagP,
                                      int* __restrict__ counter) {
  if (blockIdx.x == 0 && threadIdx.x == 0)
    __hip_atomic_store(counter, 0, __ATOMIC_RELAXED, __HIP_MEMORY_SCOPE_AGENT);
  __shared__ float rowc[16];
  const int t = threadIdx.x;
  const int rl = t >> 4, l16 = t & 15;
  const int row = blockIdx.x * 16 + rl;
  const float* ar = anc + (size_t)row * D + l16 * 8;
  const float* pr = pos + (size_t)row * D + l16 * 8;
  float4 a0 = *(const float4*)ar, a1 = *(const float4*)(ar + 4);
  float4 p0 = *(const float4*)pr, p1 = *(const float4*)(pr + 4);
  float av[8] = {a0.x, a0.y, a0.z, a0.w, a1.x, a1.y, a1.z, a1.w};
  float pv[8] = {p0.x, p0.y, p0.z, p0.w, p1.x, p1.y, p1.z, p1.w};
  float ssa = 0.f, ssp = 0.f;
#pragma unroll
  for (int k = 0; k < 8; ++k) { ssa += av[k] * av[k]; ssp += pv[k] * pv[k]; }
#pragma unroll
  for (int off = 1; off < 16; off <<= 1) {
    ssa += __shfl_xor(ssa, off);
    ssp += __shfl_xor(ssp, off);
  }
  const float sa = 1.f / fmaxf(sqrtf(ssa), 1e-8f);
  const float sp = 1.f / fmaxf(sqrtf(ssp), 1e-8f);
  float an[8], pn[8];
  float dot = 0.f;
#pragma unroll
  for (int k = 0; k < 8; ++k) {
    an[k] = av[k] * sa;
    pn[k] = pv[k] * sp;
    dot += an[k] * pn[k];
  }
  int wa0 = __builtin_amdgcn_cvt_pk_fp8_f32(an[0], an[1], 0, false);
  wa0 = __builtin_amdgcn_cvt_pk_fp8_f32(an[2], an[3], wa0, true);
  int wa1 = __builtin_amdgcn_cvt_pk_fp8_f32(an[4], an[5], 0, false);
  wa1 = __builtin_amdgcn_cvt_pk_fp8_f32(an[6], an[7], wa1, true);
  int wp0 = __builtin_amdgcn_cvt_pk_fp8_f32(pn[0], pn[1], 0, false);
  wp0 = __builtin_amdgcn_cvt_pk_fp8_f32(pn[2], pn[3], wp0, true);
  int wp1 = __builtin_amdgcn_cvt_pk_fp8_f32(pn[4], pn[5], 0, false);
  wp1 = __builtin_amdgcn_cvt_pk_fp8_f32(pn[6], pn[7], wp1, true);
  *(int2*)(wsA + (size_t)row * D + l16 * 8) = make_int2(wa0, wa1);
  *(int2*)(wsP + (size_t)row * D + l16 * 8) = make_int2(wp0, wp1);
#pragma unroll
  for (int off = 1; off < 16; off <<= 1) dot += __shfl_xor(dot, off);
  if (l16 == 0) rowc[rl] = 1.f - dot - fmaxf(dot, 0.f);
  __syncthreads();
  if (t == 0) {
    float s = 0.f;
#pragma unroll
    for (int i = 0; i < 16; ++i) s += rowc[i];
    diagP[blockIdx.x] = s;
  }
}

// ---------------------------------------------------------------------------
// fp8 MX GEMM, occupancy-first: 512 blocks x 512 thr (8 waves, 2 wrow x 4
// wcol), wave tile 64x32 -> lean regs (af[4]=32 + acc[4][2]=32 + bfr[2]=16
// ~100 live, launch_bounds(512,4) cap 128, no spill). Block = 128-row panel
// x 1024-col group (8 col tiles of 128). LDS = A 16KB + B dbuf 32KB = 48KB
// -> 2 blocks/CU = 4 waves/SIMD (2x every prior round; latency hiding via
// TLP). R6-validated loop structure; ticket-fused finalize (R8-validated).
// ---------------------------------------------------------------------------
__global__ __launch_bounds__(512, 4) void gemm_relu_sum_kernel(
    const unsigned char* __restrict__ wsA,
    const unsigned char* __restrict__ wsP,
    float* __restrict__ partials, const float* __restrict__ diagP,
    int* __restrict__ counter, float* __restrict__ out, float invBB) {
  __shared__ __align__(16) unsigned char ldsA[128 * 128];      // 16 KB
  __shared__ __align__(16) unsigned char ldsB[2][128 * 128];   // 2 x 16 KB
  __shared__ float wpart[8];
  __shared__ int lastFlag;
  const int tid = threadIdx.x;
  const int bid = blockIdx.x;
  const int w = tid >> 6, l = tid & 63;
  const int r16 = l & 15, kg = l >> 4;
  const int wrow = w >> 2, wcol = w & 3;   // wave tile 64 rows x 32 cols
  const int rp = bid >> 3;                 // row panel 0..63 (128 rows)
  const int cg = bid & 7;                  // col group 0..7 (XCD-pinned)

  // ---- stage A panel (16KB, 2 insts/thread): linear dest, swizzled source
  const unsigned char* gA = wsA + (size_t)rp * 128 * D;
#pragma unroll
  for (int it = 0; it < 2; ++it) {
    const int g = it * 512 + tid;          // 16B chunk 0..1023
    const int r = g >> 3, sl = g & 7;
    const int goff = r * 128 + ((sl ^ (r & 7)) * 16);
    const int lbase = (it * 512 + w * 64) * 16;
    __builtin_amdgcn_global_load_lds(
        (const __attribute__((address_space(1))) char*)(gA + goff),
        (__attribute__((address_space(3))) char*)((char*)ldsA + lbase), 16, 0, 0);
  }
  // ---- stage B tile 0
  {
    const unsigned char* gBt = wsP + (size_t)(cg * 1024) * D;
#pragma unroll
    for (int it = 0; it < 2; ++it) {
      const int g = it * 512 + tid;
      const int r = g >> 3, sl = g & 7;
      const int goff = r * 128 + ((sl ^ (r & 7)) * 16);
      const int lbase = (it * 512 + w * 64) * 16;
      __builtin_amdgcn_global_load_lds(
          (const __attribute__((address_space(1))) char*)(gBt + goff),
          (__attribute__((address_space(3))) char*)((char*)ldsB[0] + lbase), 16, 0, 0);
    }
  }
  __syncthreads();

  // ---- hoist A fragments (4 x 32B = 32 VGPR), reused across all 8 tiles
  i32x8 af[4];
#pragma unroll
  for (int m = 0; m < 4; ++m) {
    const int r = wrow * 64 + m * 16 + r16;
    const unsigned char* base = (const unsigned char*)ldsA + r * 128;
    i32x4 lo = *(const i32x4*)(base + (((2 * kg) ^ (r & 7)) * 16));
    i32x4 hi = *(const i32x4*)(base + (((2 * kg + 1) ^ (r & 7)) * 16));
    af[m] = __builtin_shufflevector(lo, hi, 0, 1, 2, 3, 4, 5, 6, 7);
  }

  float s0 = 0.f, s1 = 0.f, s2 = 0.f, s3 = 0.f;
  for (int t = 0; t < 8; ++t) {
    if (t < 7) {   // stage next B tile (hides under compute via TLP)
      const unsigned char* gBt = wsP + (size_t)(cg * 1024 + (t + 1) * 128) * D;
      char* lB = (char*)ldsB[(t + 1) & 1];
#pragma unroll
      for (int it = 0; it < 2; ++it) {
        const int g = it * 512 + tid;
        const int r = g >> 3, sl = g & 7;
        const int goff = r * 128 + ((sl ^ (r & 7)) * 16);
        const int lbase = (it * 512 + w * 64) * 16;
        __builtin_amdgcn_global_load_lds(
            (const __attribute__((address_space(1))) char*)(gBt + goff),
            (__attribute__((address_space(3))) char*)(lB + lbase), 16, 0, 0);
      }
    }

    const unsigned char* lB = (const unsigned char*)ldsB[t & 1];
    i32x8 bfr[2];
#pragma unroll
    for (int n = 0; n < 2; ++n) {
      const int r = wcol * 32 + n * 16 + r16;
      const unsigned char* base = lB + r * 128;
      i32x4 lo = *(const i32x4*)(base + (((2 * kg) ^ (r & 7)) * 16));
      i32x4 hi = *(const i32x4*)(base + (((2 * kg + 1) ^ (r & 7)) * 16));
      bfr[n] = __builtin_shufflevector(lo, hi, 0, 1, 2, 3, 4, 5, 6, 7);
    }

    f32x4 acc[4][2] = {};
    __builtin_amdgcn_s_setprio(1);
#pragma unroll
    for (int m = 0; m < 4; ++m)
#pragma unroll
      for (int n = 0; n < 2; ++n)
        acc[m][n] = __builtin_amdgcn_mfma_scale_f32_16x16x128_f8f6f4(
            af[m], bfr[n], acc[m][n], 0, 0,   // cbsz=fp8, blgp=fp8
            0, 0x7f7f7f7f, 0, 0x7f7f7f7f);    // scales = 1.0
    __builtin_amdgcn_s_setprio(0);

#pragma unroll
    for (int m = 0; m < 4; ++m)
#pragma unroll
      for (int n = 0; n < 2; ++n) {
        s0 += fmaxf(acc[m][n][0], 0.f);
        s1 += fmaxf(acc[m][n][1], 0.f);
        s2 += fmaxf(acc[m][n][2], 0.f);
        s3 += fmaxf(acc[m][n][3], 0.f);
      }

    __syncthreads();
  }

  // ---- block partial + ticket-fused finalize (R8-validated pattern)
  float s = (s0 + s1) + (s2 + s3);
#pragma unroll
  for (int off = 32; off >= 1; off >>= 1) s += __shfl_xor(s, off);
  if (l == 0) wpart[w] = s;
  __syncthreads();
  if (tid == 0) {
    float b = 0.f;
#pragma unroll
    for (int i = 0; i < 8; ++i) b += wpart[i];
    __hip_atomic_store(&partials[bid], b, __ATOMIC_RELAXED,
                       __HIP_MEMORY_SCOPE_AGENT);
    __threadfence();
    const int ticket = __hip_atomic_fetch_add(counter, 1, __ATOMIC_ACQ_REL,
                                              __HIP_MEMORY_SCOPE_AGENT);
    lastFlag = (ticket == GBLK - 1) ? 1 : 0;
  }
  __syncthreads();

  if (lastFlag) {
    __threadfence();
    float v = diagP[tid] +
              __hip_atomic_load(&partials[tid], __ATOMIC_RELAXED,
                                __HIP_MEMORY_SCOPE_AGENT);
#pragma unroll
    for (int off = 32; off >= 1; off >>= 1) v += __shfl_xor(v, off);
    if (l == 0) wpart[w] = v;
    __syncthreads();
    if (tid == 0) {
      float tot = 0.f;
#pragma unroll
      for (int i = 0; i < 8; ++i) tot += wpart[i];
      out[0] = tot * invBB;
    }
  }
}

extern "C" void kernel_launch(void* const* d_in, const int* in_sizes, int n_in,
                              void* d_out, int out_size, void* d_ws, size_t ws_size,
                              hipStream_t stream) {
  const float* pos = (const float*)d_in[0];  // hid_positive
  const float* anc = (const float*)d_in[1];  // hid_anchor
  const int B = in_sizes[0] / D;             // 8192

  char* ws = (char*)d_ws;
  unsigned char* wsA = (unsigned char*)ws;                      // B*D fp8 (1MB)
  unsigned char* wsP = (unsigned char*)(ws + (size_t)B * D);    // B*D fp8 (1MB)
  float* partials = (float*)(ws + (size_t)2 * B * D);           // 512 f32
  float* diagP = partials + GBLK;                               // 512 f32
  int* counter = (int*)(diagP + 512);

  const int nDiag = B / 16;                  // 512
  const float invBB = 1.0f / ((float)B * (float)B);

  normalize_diag_kernel<<<nDiag, 256, 0, stream>>>(anc, pos, wsA, wsP, diagP,
                                                   counter);
  gemm_relu_sum_kernel<<<GBLK, 512, 0, stream>>>(wsA, wsP, partials, diagP,
                                                 counter, (float*)d_out, invBB);
}

// Round 12
// 30.534 us; speedup vs baseline: 2.9407x; 1.1829x over previous
//
#include <hip/hip_runtime.h>

typedef float f32x4 __attribute__((ext_vector_type(4)));
typedef int   i32x4 __attribute__((ext_vector_type(4)));
typedef int   i32x8 __attribute__((ext_vector_type(8)));

#define D 128
#define NBLK 256   // 16 row-panels x 16 col-panels (512x512 tiles)

// ---------------------------------------------------------------------------
// Normalize: one block = 16 rows x 16 lanes. fp8(e4m3) normalized rows -> ws,
// exact-f32 diag partial -> diagP[bid]; block 0 zeroes the gemm ticket.
// (Validated verbatim since R5: absmax 0.0.)
// ---------------------------------------------------------------------------
__global__ void normalize_diag_kernel(const float* __restrict__ anc,
                                      const float* __restrict__ pos,
                                      unsigned char* __restrict__ wsA,
                                      unsigned char* __restrict__ wsP,
                                      float* __restrict__ diagP,
                                      int* __restrict__ counter) {
  if (blockIdx.x == 0 && threadIdx.x == 0)
    __hip_atomic_store(counter, 0, __ATOMIC_RELAXED, __HIP_MEMORY_SCOPE_AGENT);
  __shared__ float rowc[16];
  const int t = threadIdx.x;
  const int rl = t >> 4, l16 = t & 15;
  const int row = blockIdx.x * 16 + rl;
  const float* ar = anc + (size_t)row * D + l16 * 8;
  const float* pr = pos + (size_t)row * D + l16 * 8;
  float4 a0 = *(const float4*)ar, a1 = *(const float4*)(ar + 4);
  float4 p0 = *(const float4*)pr, p1 = *(const float4*)(pr + 4);
  float av[8] = {a0.x, a0.y, a0.z, a0.w, a1.x, a1.y, a1.z, a1.w};
  float pv[8] = {p0.x, p0.y, p0.z, p0.w, p1.x, p1.y, p1.z, p1.w};
  float ssa = 0.f, ssp = 0.f;
#pragma unroll
  for (int k = 0; k < 8; ++k) { ssa += av[k] * av[k]; ssp += pv[k] * pv[k]; }
#pragma unroll
  for (int off = 1; off < 16; off <<= 1) {
    ssa += __shfl_xor(ssa, off);
    ssp += __shfl_xor(ssp, off);
  }
  const float sa = 1.f / fmaxf(sqrtf(ssa), 1e-8f);
  const float sp = 1.f / fmaxf(sqrtf(ssp), 1e-8f);
  float an[8], pn[8];
  float dot = 0.f;
#pragma unroll
  for (int k = 0; k < 8; ++k) {
    an[k] = av[k] * sa;
    pn[k] = pv[k] * sp;
    dot += an[k] * pn[k];
  }
  int wa0 = __builtin_amdgcn_cvt_pk_fp8_f32(an[0], an[1], 0, false);
  wa0 = __builtin_amdgcn_cvt_pk_fp8_f32(an[2], an[3], wa0, true);
  int wa1 = __builtin_amdgcn_cvt_pk_fp8_f32(an[4], an[5], 0, false);
  wa1 = __builtin_amdgcn_cvt_pk_fp8_f32(an[6], an[7], wa1, true);
  int wp0 = __builtin_amdgcn_cvt_pk_fp8_f32(pn[0], pn[1], 0, false);
  wp0 = __builtin_amdgcn_cvt_pk_fp8_f32(pn[2], pn[3], wp0, true);
  int wp1 = __builtin_amdgcn_cvt_pk_fp8_f32(pn[4], pn[5], 0, false);
  wp1 = __builtin_amdgcn_cvt_pk_fp8_f32(pn[6], pn[7], wp1, true);
  *(int2*)(wsA + (size_t)row * D + l16 * 8) = make_int2(wa0, wa1);
  *(int2*)(wsP + (size_t)row * D + l16 * 8) = make_int2(wp0, wp1);
#pragma unroll
  for (int off = 1; off < 16; off <<= 1) dot += __shfl_xor(dot, off);
  if (l16 == 0) rowc[rl] = 1.f - dot - fmaxf(dot, 0.f);
  __syncthreads();
  if (t == 0) {
    float s = 0.f;
#pragma unroll
    for (int i = 0; i < 16; ++i) s += rowc[i];
    diagP[blockIdx.x] = s;
  }
}

// ---------------------------------------------------------------------------
// Single-round LDS-resident fp8-MX GEMM: 256 blocks (1/CU), 8 waves (4x2).
// Block = 512x512 output tile; A panel (512x128 fp8 = 64KB) and B panel
// (64KB) staged ONCE via global_load_lds (swizzled source, linear dest).
// No loop staging, no inter-iteration barriers: af[8] hoisted, then 8 pure
// register iterations {bfr ds_read -> 16 mfma_scale -> relu}. MFMA-bound by
// construction (~3.7us matrix-pipe vs ~1.6us LDS, ~1.7us VALU on parallel
// pipes). Epilogue: relu-sum partial + ticket-fused finalize (validated).
// ---------------------------------------------------------------------------
__global__ __launch_bounds__(512, 2) void gemm_relu_sum_kernel(
    const unsigned char* __restrict__ wsA,
    const unsigned char* __restrict__ wsP,
    float* __restrict__ partials, const float* __restrict__ diagP,
    int* __restrict__ counter, float* __restrict__ out, float invBB) {
  __shared__ __align__(16) unsigned char lds[131072];   // A 64KB | B 64KB
  unsigned char* ldsA = lds;
  unsigned char* ldsB = lds + 65536;

  const int tid = threadIdx.x;
  const int bid = blockIdx.x;
  const int w = tid >> 6, l = tid & 63;
  const int r16 = l & 15, kg = l >> 4;
  const int wrow = w >> 1, wcol = w & 1;   // wave = 128 rows x 256 cols
  const int rp = bid >> 4;                 // row panel 0..15 (512 rows)
  const int cp = bid & 15;                 // col panel 0..15 (512 cols)

  // ---- stage both panels once (8+8 insts/thread), swizzled global source
  const unsigned char* gA = wsA + (size_t)rp * 512 * D;
  const unsigned char* gB = wsP + (size_t)cp * 512 * D;
#pragma unroll
  for (int it = 0; it < 8; ++it) {
    const int g = it * 512 + tid;          // 16B chunk 0..4095
    const int r = g >> 3, sl = g & 7;
    const int goff = r * 128 + ((sl ^ (r & 7)) * 16);
    const int lbase = (it * 512 + w * 64) * 16;
    __builtin_amdgcn_global_load_lds(
        (const __attribute__((address_space(1))) char*)(gA + goff),
        (__attribute__((address_space(3))) char*)((char*)ldsA + lbase), 16, 0, 0);
    __builtin_amdgcn_global_load_lds(
        (const __attribute__((address_space(1))) char*)(gB + goff),
        (__attribute__((address_space(3))) char*)((char*)ldsB + lbase), 16, 0, 0);
  }
  __syncthreads();

  // ---- hoist A fragments once (8 x 32B = 64 VGPR)
  i32x8 af[8];
#pragma unroll
  for (int m = 0; m < 8; ++m) {
    const int r = wrow * 128 + m * 16 + r16;
    const unsigned char* base = ldsA + r * 128;
    i32x4 lo = *(const i32x4*)(base + (((2 * kg) ^ (r & 7)) * 16));
    i32x4 hi = *(const i32x4*)(base + (((2 * kg + 1) ^ (r & 7)) * 16));
    af[m] = __builtin_shufflevector(lo, hi, 0, 1, 2, 3, 4, 5, 6, 7);
  }

  // ---- 8 pure-register iterations over this wave's 256 columns
  float s0 = 0.f, s1 = 0.f, s2 = 0.f, s3 = 0.f;
#pragma unroll
  for (int ct = 0; ct < 8; ++ct) {
    i32x8 bfr[2];
#pragma unroll
    for (int n = 0; n < 2; ++n) {
      const int r = wcol * 256 + ct * 32 + n * 16 + r16;
      const unsigned char* base = ldsB + r * 128;
      i32x4 lo = *(const i32x4*)(base + (((2 * kg) ^ (r & 7)) * 16));
      i32x4 hi = *(const i32x4*)(base + (((2 * kg + 1) ^ (r & 7)) * 16));
      bfr[n] = __builtin_shufflevector(lo, hi, 0, 1, 2, 3, 4, 5, 6, 7);
    }
    f32x4 acc[8][2] = {};
    __builtin_amdgcn_s_setprio(1);
#pragma unroll
    for (int m = 0; m < 8; ++m)
#pragma unroll
      for (int n = 0; n < 2; ++n)
        acc[m][n] = __builtin_amdgcn_mfma_scale_f32_16x16x128_f8f6f4(
            af[m], bfr[n], acc[m][n], 0, 0,   // cbsz=fp8, blgp=fp8
            0, 0x7f7f7f7f, 0, 0x7f7f7f7f);    // scales = 1.0
    __builtin_amdgcn_s_setprio(0);
#pragma unroll
    for (int m = 0; m < 8; ++m)
#pragma unroll
      for (int n = 0; n < 2; ++n) {
        s0 += fmaxf(acc[m][n][0], 0.f);
        s1 += fmaxf(acc[m][n][1], 0.f);
        s2 += fmaxf(acc[m][n][2], 0.f);
        s3 += fmaxf(acc[m][n][3], 0.f);
      }
  }

  // ---- block partial + ticket-fused finalize (reuse LDS as scratch)
  __syncthreads();
  float* wpart = (float*)lds;
  int* lastFlag = (int*)(lds + 64);

  float s = (s0 + s1) + (s2 + s3);
#pragma unroll
  for (int off = 32; off >= 1; off >>= 1) s += __shfl_xor(s, off);
  if (l == 0) wpart[w] = s;
  __syncthreads();
  if (tid == 0) {
    float b = 0.f;
#pragma unroll
    for (int i = 0; i < 8; ++i) b += wpart[i];
    __hip_atomic_store(&partials[bid], b, __ATOMIC_RELAXED,
                       __HIP_MEMORY_SCOPE_AGENT);
    __threadfence();
    const int ticket = __hip_atomic_fetch_add(counter, 1, __ATOMIC_ACQ_REL,
                                              __HIP_MEMORY_SCOPE_AGENT);
    lastFlag[0] = (ticket == NBLK - 1) ? 1 : 0;
  }
  __syncthreads();

  if (lastFlag[0]) {
    __threadfence();
    float v = diagP[tid];                 // 512 diag partials
    if (tid < NBLK)
      v += __hip_atomic_load(&partials[tid], __ATOMIC_RELAXED,
                             __HIP_MEMORY_SCOPE_AGENT);
#pragma unroll
    for (int off = 32; off >= 1; off >>= 1) v += __shfl_xor(v, off);
    if (l == 0) wpart[w] = v;
    __syncthreads();
    if (tid == 0) {
      float tot = 0.f;
#pragma unroll
      for (int i = 0; i < 8; ++i) tot += wpart[i];
      out[0] = tot * invBB;
    }
  }
}

extern "C" void kernel_launch(void* const* d_in, const int* in_sizes, int n_in,
                              void* d_out, int out_size, void* d_ws, size_t ws_size,
                              hipStream_t stream) {
  const float* pos = (const float*)d_in[0];  // hid_positive
  const float* anc = (const float*)d_in[1];  // hid_anchor
  const int B = in_sizes[0] / D;             // 8192

  char* ws = (char*)d_ws;
  unsigned char* wsA = (unsigned char*)ws;                      // B*D fp8 (1MB)
  unsigned char* wsP = (unsigned char*)(ws + (size_t)B * D);    // B*D fp8 (1MB)
  float* partials = (float*)(ws + (size_t)2 * B * D);           // 256 f32
  float* diagP = partials + NBLK;                               // 512 f32
  int* counter = (int*)(diagP + 512);

  const int nDiag = B / 16;                  // 512
  const float invBB = 1.0f / ((float)B * (float)B);

  normalize_diag_kernel<<<nDiag, 256, 0, stream>>>(anc, pos, wsA, wsP, diagP,
                                                   counter);
  gemm_relu_sum_kernel<<<NBLK, 512, 0, stream>>>(wsA, wsP, partials, diagP,
                                                 counter, (float*)d_out, invBB);
}